// Round 1
// baseline (655.568 us; speedup 1.0000x reference)
//
#include <hip/hip_runtime.h>

#define NA    69      // 3 * (4*6 - 1) angles
#define KDIM  512
#define BLK   256
#define KC    32      // K-chunk staged in LDS
#define LSTRIDE 33    // KC + 1 pad -> bank-staggered reads

// ---------------- gate helpers (fully inlined, constant-folded indices) ----

__device__ __forceinline__ void apply_rxx(float* sr, float* si, int w0, int w1, float th) {
    // RXX(theta): couples j <-> j^(m0|m1); new = c*own + (-i*sn)*partner
    float h = 0.5f * th;
    float c = __cosf(h), sn = __sinf(h);
    const int m0 = 1 << (5 - w0);
    const int M  = m0 | (1 << (5 - w1));
#pragma unroll
    for (int j = 0; j < 64; ++j) {
        if (j & m0) continue;          // canonical half of each orbit
        const int p = j ^ M;
        float ar = sr[j], ai = si[j], br = sr[p], bi = si[p];
        sr[j] = c * ar + sn * bi;
        si[j] = c * ai - sn * br;
        sr[p] = c * br + sn * ai;
        si[p] = c * bi - sn * ar;
    }
}

__device__ __forceinline__ void apply_u3(float* sr, float* si, int w,
                                         float th, float ph, float la) {
    // U3 = [[ct, -e^{i la} st], [e^{i ph} st, e^{i(ph+la)} ct]]
    float h = 0.5f * th;
    float ct = __cosf(h), st = __sinf(h);
    float cph = __cosf(ph), sph = __sinf(ph);
    float cla = __cosf(la), sla = __sinf(la);
    float cpl = cph * cla - sph * sla;   // cos(ph+la)
    float spl = sph * cla + cph * sla;   // sin(ph+la)
    float m01r = -cla * st, m01i = -sla * st;
    float m10r =  cph * st, m10i =  sph * st;
    float m11r =  cpl * ct, m11i =  spl * ct;
    const int m = 1 << (5 - w);
#pragma unroll
    for (int j = 0; j < 64; ++j) {
        if (j & m) continue;
        const int p = j | m;
        float ar = sr[j], ai = si[j], br = sr[p], bi = si[p];
        sr[j] = ct * ar + m01r * br - m01i * bi;
        si[j] = ct * ai + m01r * bi + m01i * br;
        sr[p] = m10r * ar - m10i * ai + m11r * br - m11i * bi;
        si[p] = m10r * ai + m10i * ar + m11r * bi + m11i * br;
    }
}

// ---------------- fused kernel: angles GEMV + circuit, one thread per row ---

__global__ __launch_bounds__(BLK, 1) void qrnn_fused(
    const float* __restrict__ x, const float* __restrict__ W,
    const float* __restrict__ b, float* __restrict__ out)
{
    const int t    = threadIdx.x;
    const int row0 = blockIdx.x * BLK;

    __shared__ float xs[BLK * LSTRIDE];   // 256 rows x 32 k (padded) = 33.8 KB

    // ---- phase 1: angles[row] = x[row,:] . W[a,:] + b[a], a = 0..68
    float acc[NA];
#pragma unroll
    for (int a = 0; a < NA; ++a) acc[a] = b[a];   // uniform -> s_load

    for (int kc = 0; kc < KDIM; kc += KC) {
        __syncthreads();   // protect previous chunk's reads
        // stage x[row0..row0+255][kc..kc+KC) coalesced
#pragma unroll
        for (int it = 0; it < 8; ++it) {
            int f4 = it * BLK + t;
            int r  = f4 >> 3;          // 8 float4 per row
            int kq = f4 & 7;
            float4 v = *reinterpret_cast<const float4*>(
                &x[(size_t)(row0 + r) * KDIM + kc + kq * 4]);
            *reinterpret_cast<float4*>(&xs[r * LSTRIDE + kq * 4]) = v;
        }
        __syncthreads();
        // my row's chunk into registers (8 x ds_read_b128, bank-staggered)
        float4 xv[KC / 4];
#pragma unroll
        for (int q = 0; q < KC / 4; ++q)
            xv[q] = *reinterpret_cast<const float4*>(&xs[t * LSTRIDE + q * 4]);
        // 69 dot-chunks; W addresses are block-uniform -> scalar loads
#pragma unroll
        for (int a = 0; a < NA; ++a) {
            const float* wa = W + a * KDIM + kc;
            float s = 0.f;
#pragma unroll
            for (int q = 0; q < KC / 4; ++q) {
                s += xv[q].x * wa[q * 4 + 0];
                s += xv[q].y * wa[q * 4 + 1];
                s += xv[q].z * wa[q * 4 + 2];
                s += xv[q].w * wa[q * 4 + 3];
            }
            acc[a] += s;
        }
    }

    // ---- phase 2: 6-qubit circuit, state in registers
    float sr[64], si[64];
#pragma unroll
    for (int j = 0; j < 64; ++j) { sr[j] = 0.f; si[j] = 0.f; }
    sr[0] = 1.f;

#pragma unroll
    for (int lay = 0; lay < 3; ++lay) {
        const int base = lay * 23;
#pragma unroll
        for (int i = 0; i < 5; ++i) {
            apply_rxx(sr, si, i, i + 1, acc[base + 4 * i]);
            apply_u3 (sr, si, i, acc[base + 4 * i + 1],
                                 acc[base + 4 * i + 2],
                                 acc[base + 4 * i + 3]);
        }
        apply_u3(sr, si, 5, acc[base + 20], acc[base + 21], acc[base + 22]);
    }

    // ---- output: (B, 2, 64) float32
    float* o = out + (size_t)(row0 + t) * 128;
#pragma unroll
    for (int j = 0; j < 64; ++j) o[j]      = sr[j];
#pragma unroll
    for (int j = 0; j < 64; ++j) o[64 + j] = si[j];
}

extern "C" void kernel_launch(void* const* d_in, const int* in_sizes, int n_in,
                              void* d_out, int out_size, void* d_ws, size_t ws_size,
                              hipStream_t stream) {
    const float* x = (const float*)d_in[0];
    const float* W = (const float*)d_in[1];
    const float* b = (const float*)d_in[2];
    float* out = (float*)d_out;
    const int batch = in_sizes[0] / KDIM;          // 65536
    const int grid  = batch / BLK;                 // 256 blocks, 256 thr
    hipLaunchKernelGGL(qrnn_fused, dim3(grid), dim3(BLK), 0, stream,
                       x, W, b, out);
}

// Round 2
// 550.228 us; speedup vs baseline: 1.1914x; 1.1914x over previous
//
#include <hip/hip_runtime.h>

#define NA    69      // 3 * (4*6 - 1) angles
#define KDIM  512
#define BLK   256
#define KC    32      // K-chunk staged in LDS
#define LSTRIDE 33    // KC + 1 pad -> bank-staggered reads

// =====================  kernel 1: angles = x @ W^T + b  =====================
// one thread per row; x staged in LDS; W via block-uniform (scalar) loads.
// Output TRANSPOSED: ang[a * pass_rows + local_row]  (coalesced stores, and
// coalesced re-load in the circuit kernel).

__global__ __launch_bounds__(BLK, 1) void angles_gemm(
    const float* __restrict__ x, const float* __restrict__ W,
    const float* __restrict__ b, float* __restrict__ ang,
    int row_base, int pass_rows)
{
    const int t     = threadIdx.x;
    const int lrow0 = blockIdx.x * BLK;

    __shared__ float xs[BLK * LSTRIDE];   // 33.8 KB

    float acc[NA];
#pragma unroll
    for (int a = 0; a < NA; ++a) acc[a] = b[a];   // uniform -> s_load

    for (int kc = 0; kc < KDIM; kc += KC) {
        __syncthreads();
#pragma unroll
        for (int it = 0; it < 8; ++it) {
            int f4 = it * BLK + t;
            int r  = f4 >> 3;          // 8 float4 per row-chunk
            int kq = f4 & 7;
            float4 v = *reinterpret_cast<const float4*>(
                &x[(size_t)(row_base + lrow0 + r) * KDIM + kc + kq * 4]);
            *reinterpret_cast<float4*>(&xs[r * LSTRIDE + kq * 4]) = v;
        }
        __syncthreads();
        float4 xv[KC / 4];
#pragma unroll
        for (int q = 0; q < KC / 4; ++q)
            xv[q] = *reinterpret_cast<const float4*>(&xs[t * LSTRIDE + q * 4]);
#pragma unroll
        for (int a = 0; a < NA; ++a) {
            const float* wa = W + a * KDIM + kc;
            float s = 0.f;
#pragma unroll
            for (int q = 0; q < KC / 4; ++q) {
                s += xv[q].x * wa[q * 4 + 0];
                s += xv[q].y * wa[q * 4 + 1];
                s += xv[q].z * wa[q * 4 + 2];
                s += xv[q].w * wa[q * 4 + 3];
            }
            acc[a] += s;
        }
    }

    const int lrow = lrow0 + t;
#pragma unroll
    for (int a = 0; a < NA; ++a)
        ang[(size_t)a * pass_rows + lrow] = acc[a];   // coalesced across lanes
}

// =====================  kernel 2: 6-qubit circuit  ==========================
// one thread per row; state (64 complex) in registers; angles staged in LDS.
// Layer loop kept ROLLED (code size), wires compile-time via templates.

template<int W0, int W1>
__device__ __forceinline__ void rxx(float* sr, float* si, float th) {
    float h = 0.5f * th;
    float c, sn;
    __sincosf(h, &sn, &c);
    constexpr int m0 = 1 << (5 - W0);
    constexpr int M  = m0 | (1 << (5 - W1));
#pragma unroll
    for (int j = 0; j < 64; ++j) {
        if (j & m0) continue;
        const int p = j ^ M;
        float ar = sr[j], ai = si[j], br = sr[p], bi = si[p];
        sr[j] = c * ar + sn * bi;
        si[j] = c * ai - sn * br;
        sr[p] = c * br + sn * ai;
        si[p] = c * bi - sn * ar;
    }
}

template<int Wq>
__device__ __forceinline__ void u3(float* sr, float* si,
                                   float th, float ph, float la) {
    float h = 0.5f * th;
    float ct, st, cph, sph, cla, sla;
    __sincosf(h,  &st,  &ct);
    __sincosf(ph, &sph, &cph);
    __sincosf(la, &sla, &cla);
    float cpl = cph * cla - sph * sla;
    float spl = sph * cla + cph * sla;
    float m01r = -cla * st, m01i = -sla * st;
    float m10r =  cph * st, m10i =  sph * st;
    float m11r =  cpl * ct, m11i =  spl * ct;
    constexpr int m = 1 << (5 - Wq);
#pragma unroll
    for (int j = 0; j < 64; ++j) {
        if (j & m) continue;
        const int p = j | m;
        float ar = sr[j], ai = si[j], br = sr[p], bi = si[p];
        sr[j] = ct * ar + m01r * br - m01i * bi;
        si[j] = ct * ai + m01r * bi + m01i * br;
        sr[p] = m10r * ar - m10i * ai + m11r * br - m11i * bi;
        si[p] = m10r * ai + m10i * ar + m11r * bi + m11i * br;
    }
}

__global__ __launch_bounds__(BLK, 2) void circuit_kernel(
    const float* __restrict__ ang, float* __restrict__ out,
    int row_base, int pass_rows)
{
    const int t     = threadIdx.x;
    const int lrow0 = blockIdx.x * BLK;

    __shared__ float as_[NA][BLK];        // 70.6 KB -> 2 blocks/CU
#pragma unroll 1
    for (int a = 0; a < NA; ++a)          // coalesced loads
        as_[a][t] = ang[(size_t)a * pass_rows + lrow0 + t];
    __syncthreads();

    float sr[64], si[64];
#pragma unroll
    for (int j = 0; j < 64; ++j) { sr[j] = 0.f; si[j] = 0.f; }
    sr[0] = 1.f;

#define ANG(i) as_[(i)][t]
#pragma unroll 1
    for (int lay = 0; lay < 3; ++lay) {
        const int base = lay * 23;
        rxx<0,1>(sr, si, ANG(base + 0));
        u3<0>(sr, si, ANG(base + 1),  ANG(base + 2),  ANG(base + 3));
        rxx<1,2>(sr, si, ANG(base + 4));
        u3<1>(sr, si, ANG(base + 5),  ANG(base + 6),  ANG(base + 7));
        rxx<2,3>(sr, si, ANG(base + 8));
        u3<2>(sr, si, ANG(base + 9),  ANG(base + 10), ANG(base + 11));
        rxx<3,4>(sr, si, ANG(base + 12));
        u3<3>(sr, si, ANG(base + 13), ANG(base + 14), ANG(base + 15));
        rxx<4,5>(sr, si, ANG(base + 16));
        u3<4>(sr, si, ANG(base + 17), ANG(base + 18), ANG(base + 19));
        u3<5>(sr, si, ANG(base + 20), ANG(base + 21), ANG(base + 22));
    }
#undef ANG

    float* o = out + (size_t)(row_base + lrow0 + t) * 128;
#pragma unroll
    for (int j = 0; j < 16; ++j)
        *reinterpret_cast<float4*>(&o[j * 4]) =
            make_float4(sr[j*4], sr[j*4+1], sr[j*4+2], sr[j*4+3]);
#pragma unroll
    for (int j = 0; j < 16; ++j)
        *reinterpret_cast<float4*>(&o[64 + j * 4]) =
            make_float4(si[j*4], si[j*4+1], si[j*4+2], si[j*4+3]);
}

// =====================  fallback: original fused kernel  ====================
// used only if ws_size is too small for even one 256-row pass (proven correct).

__global__ __launch_bounds__(BLK, 1) void qrnn_fused(
    const float* __restrict__ x, const float* __restrict__ W,
    const float* __restrict__ b, float* __restrict__ out)
{
    const int t    = threadIdx.x;
    const int row0 = blockIdx.x * BLK;
    __shared__ float xs[BLK * LSTRIDE];
    float acc[NA];
#pragma unroll
    for (int a = 0; a < NA; ++a) acc[a] = b[a];
    for (int kc = 0; kc < KDIM; kc += KC) {
        __syncthreads();
#pragma unroll
        for (int it = 0; it < 8; ++it) {
            int f4 = it * BLK + t;
            int r  = f4 >> 3;
            int kq = f4 & 7;
            float4 v = *reinterpret_cast<const float4*>(
                &x[(size_t)(row0 + r) * KDIM + kc + kq * 4]);
            *reinterpret_cast<float4*>(&xs[r * LSTRIDE + kq * 4]) = v;
        }
        __syncthreads();
        float4 xv[KC / 4];
#pragma unroll
        for (int q = 0; q < KC / 4; ++q)
            xv[q] = *reinterpret_cast<const float4*>(&xs[t * LSTRIDE + q * 4]);
#pragma unroll
        for (int a = 0; a < NA; ++a) {
            const float* wa = W + a * KDIM + kc;
            float s = 0.f;
#pragma unroll
            for (int q = 0; q < KC / 4; ++q) {
                s += xv[q].x * wa[q * 4 + 0];
                s += xv[q].y * wa[q * 4 + 1];
                s += xv[q].z * wa[q * 4 + 2];
                s += xv[q].w * wa[q * 4 + 3];
            }
            acc[a] += s;
        }
    }
    float sr[64], si[64];
#pragma unroll
    for (int j = 0; j < 64; ++j) { sr[j] = 0.f; si[j] = 0.f; }
    sr[0] = 1.f;
#pragma unroll 1
    for (int lay = 0; lay < 3; ++lay) {
        const int base = lay * 23;
        rxx<0,1>(sr, si, acc[base + 0]);
        u3<0>(sr, si, acc[base + 1],  acc[base + 2],  acc[base + 3]);
        rxx<1,2>(sr, si, acc[base + 4]);
        u3<1>(sr, si, acc[base + 5],  acc[base + 6],  acc[base + 7]);
        rxx<2,3>(sr, si, acc[base + 8]);
        u3<2>(sr, si, acc[base + 9],  acc[base + 10], acc[base + 11]);
        rxx<3,4>(sr, si, acc[base + 12]);
        u3<3>(sr, si, acc[base + 13], acc[base + 14], acc[base + 15]);
        rxx<4,5>(sr, si, acc[base + 16]);
        u3<4>(sr, si, acc[base + 17], acc[base + 18], acc[base + 19]);
        u3<5>(sr, si, acc[base + 20], acc[base + 21], acc[base + 22]);
    }
    float* o = out + (size_t)(row0 + t) * 128;
#pragma unroll
    for (int j = 0; j < 64; ++j) o[j]      = sr[j];
#pragma unroll
    for (int j = 0; j < 64; ++j) o[64 + j] = si[j];
}

// ============================================================================

extern "C" void kernel_launch(void* const* d_in, const int* in_sizes, int n_in,
                              void* d_out, int out_size, void* d_ws, size_t ws_size,
                              hipStream_t stream) {
    const float* x = (const float*)d_in[0];
    const float* W = (const float*)d_in[1];
    const float* b = (const float*)d_in[2];
    float* out = (float*)d_out;
    float* ws  = (float*)d_ws;
    const int batch = in_sizes[0] / KDIM;          // 65536

    // rows per pass limited by workspace (need NA floats per row)
    size_t max_rows = ws_size / ((size_t)NA * sizeof(float));
    int rows_per_pass = (int)((max_rows / BLK) * BLK);
    if (rows_per_pass > batch) rows_per_pass = batch;

    if (rows_per_pass <= 0) {   // workspace too small: fused fallback
        hipLaunchKernelGGL(qrnn_fused, dim3(batch / BLK), dim3(BLK), 0, stream,
                           x, W, b, out);
        return;
    }

    for (int r0 = 0; r0 < batch; r0 += rows_per_pass) {
        int pr = batch - r0;
        if (pr > rows_per_pass) pr = rows_per_pass;
        hipLaunchKernelGGL(angles_gemm, dim3(pr / BLK), dim3(BLK), 0, stream,
                           x, W, b, ws, r0, pr);
        hipLaunchKernelGGL(circuit_kernel, dim3(pr / BLK), dim3(BLK), 0, stream,
                           ws, out, r0, pr);
    }
}

// Round 3
// 111.424 us; speedup vs baseline: 5.8835x; 4.9381x over previous
//
#include <hip/hip_runtime.h>

#define NA    69      // 3 * (4*6 - 1) angles
#define NP    80      // padded to 5 x 16 MFMA n-tiles
#define KDIM  512
#define BLK   256
#define KC    32
#define LSTRIDE 33

typedef __attribute__((ext_vector_type(8))) short short8v;   // 8 bf16 = 4 VGPR
typedef __attribute__((ext_vector_type(4))) float f32x4;

__device__ __forceinline__ unsigned short bf16_rne(float x) {
    unsigned u = __float_as_uint(x);
    unsigned r = u + 0x7FFF + ((u >> 16) & 1);
    return (unsigned short)(r >> 16);
}

// ============ init: W (69x512 f32) -> padded bf16 hi/lo (80x512 each) =======
__global__ void w_convert(const float* __restrict__ W,
                          unsigned short* __restrict__ Wh,
                          unsigned short* __restrict__ Wl)
{
    int idx = blockIdx.x * blockDim.x + threadIdx.x;   // 80*512 elements
    if (idx >= NP * KDIM) return;
    int n = idx / KDIM;
    float w = (n < NA) ? W[(size_t)n * KDIM + (idx % KDIM)] : 0.f;
    unsigned short h = bf16_rne(w);
    float hf = __uint_as_float((unsigned)h << 16);
    unsigned short l = bf16_rne(w - hf);
    Wh[idx] = h;
    Wl[idx] = l;
}

// ============ angles = x @ W^T + b via bf16 hi/lo MFMA ======================
// block: 256 thr = 4 waves; each wave owns 32 rows (2 m-tiles) x 80 n (5 tiles)
// output transposed: ang[n * batch + m]  (coalesced float4 stores)

__global__ __launch_bounds__(BLK, 2) void angles_mfma(
    const float* __restrict__ x,
    const unsigned short* __restrict__ Wh, const unsigned short* __restrict__ Wl,
    const float* __restrict__ b, float* __restrict__ ang, int batch)
{
    const int t    = threadIdx.x;
    const int lane = t & 63;
    const int wave = t >> 6;
    const int mb   = blockIdx.x * 128 + wave * 32;   // this wave's first row

    const int arow = lane & 15;          // A/B fragment row selector
    const int kgrp = (lane >> 4) * 8;    // K sub-offset within 32-step

    f32x4 acc[2][5];
#pragma unroll
    for (int mt = 0; mt < 2; ++mt)
#pragma unroll
        for (int nt = 0; nt < 5; ++nt) acc[mt][nt] = (f32x4){0.f, 0.f, 0.f, 0.f};

#pragma unroll 4
    for (int ks = 0; ks < KDIM / 32; ++ks) {
        const int kb = ks * 32 + kgrp;

        // ---- A fragments: x rows, hi/lo bf16
        short8v ah[2], al[2];
#pragma unroll
        for (int mt = 0; mt < 2; ++mt) {
            const float* xp = x + (size_t)(mb + mt * 16 + arow) * KDIM + kb;
            float4 v0 = *reinterpret_cast<const float4*>(xp);
            float4 v1 = *reinterpret_cast<const float4*>(xp + 4);
            float xv[8] = {v0.x, v0.y, v0.z, v0.w, v1.x, v1.y, v1.z, v1.w};
#pragma unroll
            for (int j = 0; j < 8; ++j) {
                unsigned short h = bf16_rne(xv[j]);
                float hf = __uint_as_float((unsigned)h << 16);
                ah[mt][j] = (short)h;
                al[mt][j] = (short)bf16_rne(xv[j] - hf);
            }
        }

        // ---- B fragments: W rows (already bf16 hi/lo, K-major like A)
        short8v bh[5], bl[5];
#pragma unroll
        for (int nt = 0; nt < 5; ++nt) {
            size_t off = (size_t)(nt * 16 + arow) * KDIM + kb;
            bh[nt] = *reinterpret_cast<const short8v*>(Wh + off);
            bl[nt] = *reinterpret_cast<const short8v*>(Wl + off);
        }

        // ---- 3-product fp32-emulation MFMA
#pragma unroll
        for (int mt = 0; mt < 2; ++mt)
#pragma unroll
            for (int nt = 0; nt < 5; ++nt) {
                acc[mt][nt] = __builtin_amdgcn_mfma_f32_16x16x32_bf16(
                    ah[mt], bh[nt], acc[mt][nt], 0, 0, 0);
                acc[mt][nt] = __builtin_amdgcn_mfma_f32_16x16x32_bf16(
                    al[mt], bh[nt], acc[mt][nt], 0, 0, 0);
                acc[mt][nt] = __builtin_amdgcn_mfma_f32_16x16x32_bf16(
                    ah[mt], bl[nt], acc[mt][nt], 0, 0, 0);
            }
    }

    // ---- epilogue: C layout col=lane&15 (n), row=(lane>>4)*4+j (m)
    // j=0..3 are 4 consecutive m at fixed n -> float4 store into ang[n][m]
#pragma unroll
    for (int mt = 0; mt < 2; ++mt)
#pragma unroll
        for (int nt = 0; nt < 5; ++nt) {
            int n = nt * 16 + (lane & 15);
            if (n < NA) {
                float bias = b[n];
                int m = mb + mt * 16 + (lane >> 4) * 4;
                f32x4 v = acc[mt][nt];
                float4 o = make_float4(v[0] + bias, v[1] + bias,
                                       v[2] + bias, v[3] + bias);
                *reinterpret_cast<float4*>(&ang[(size_t)n * batch + m]) = o;
            }
        }
}

// ============ circuit: one thread per row, state in registers ===============

template<int W0, int W1>
__device__ __forceinline__ void rxx(float* sr, float* si, float th) {
    float h = 0.5f * th;
    float c, sn;
    __sincosf(h, &sn, &c);
    constexpr int m0 = 1 << (5 - W0);
    constexpr int M  = m0 | (1 << (5 - W1));
#pragma unroll
    for (int j = 0; j < 64; ++j) {
        if (j & m0) continue;
        const int p = j ^ M;
        float ar = sr[j], ai = si[j], br = sr[p], bi = si[p];
        sr[j] = c * ar + sn * bi;
        si[j] = c * ai - sn * br;
        sr[p] = c * br + sn * ai;
        si[p] = c * bi - sn * ar;
    }
}

template<int Wq>
__device__ __forceinline__ void u3(float* sr, float* si,
                                   float th, float ph, float la) {
    float h = 0.5f * th;
    float ct, st, cph, sph, cla, sla;
    __sincosf(h,  &st,  &ct);
    __sincosf(ph, &sph, &cph);
    __sincosf(la, &sla, &cla);
    float cpl = cph * cla - sph * sla;
    float spl = sph * cla + cph * sla;
    float m01r = -cla * st, m01i = -sla * st;
    float m10r =  cph * st, m10i =  sph * st;
    float m11r =  cpl * ct, m11i =  spl * ct;
    constexpr int m = 1 << (5 - Wq);
#pragma unroll
    for (int j = 0; j < 64; ++j) {
        if (j & m) continue;
        const int p = j | m;
        float ar = sr[j], ai = si[j], br = sr[p], bi = si[p];
        sr[j] = ct * ar + m01r * br - m01i * bi;
        si[j] = ct * ai + m01r * bi + m01i * br;
        sr[p] = m10r * ar - m10i * ai + m11r * br - m11i * bi;
        si[p] = m10r * ai + m10i * ar + m11r * bi + m11i * br;
    }
}

__global__ __launch_bounds__(BLK, 2) void circuit_kernel(
    const float* __restrict__ ang, float* __restrict__ out,
    int row_base, int pass_rows)
{
    const int t     = threadIdx.x;
    const int lrow0 = blockIdx.x * BLK;

    __shared__ float as_[NA][BLK];
#pragma unroll 1
    for (int a = 0; a < NA; ++a)
        as_[a][t] = ang[(size_t)a * pass_rows + lrow0 + t];
    __syncthreads();

    float sr[64], si[64];
#pragma unroll
    for (int j = 0; j < 64; ++j) { sr[j] = 0.f; si[j] = 0.f; }
    sr[0] = 1.f;

#define ANG(i) as_[(i)][t]
#pragma unroll 1
    for (int lay = 0; lay < 3; ++lay) {
        const int base = lay * 23;
        rxx<0,1>(sr, si, ANG(base + 0));
        u3<0>(sr, si, ANG(base + 1),  ANG(base + 2),  ANG(base + 3));
        rxx<1,2>(sr, si, ANG(base + 4));
        u3<1>(sr, si, ANG(base + 5),  ANG(base + 6),  ANG(base + 7));
        rxx<2,3>(sr, si, ANG(base + 8));
        u3<2>(sr, si, ANG(base + 9),  ANG(base + 10), ANG(base + 11));
        rxx<3,4>(sr, si, ANG(base + 12));
        u3<3>(sr, si, ANG(base + 13), ANG(base + 14), ANG(base + 15));
        rxx<4,5>(sr, si, ANG(base + 16));
        u3<4>(sr, si, ANG(base + 17), ANG(base + 18), ANG(base + 19));
        u3<5>(sr, si, ANG(base + 20), ANG(base + 21), ANG(base + 22));
    }
#undef ANG

    float* o = out + (size_t)(row_base + lrow0 + t) * 128;
#pragma unroll
    for (int j = 0; j < 16; ++j)
        *reinterpret_cast<float4*>(&o[j * 4]) =
            make_float4(sr[j*4], sr[j*4+1], sr[j*4+2], sr[j*4+3]);
#pragma unroll
    for (int j = 0; j < 16; ++j)
        *reinterpret_cast<float4*>(&o[64 + j * 4]) =
            make_float4(si[j*4], si[j*4+1], si[j*4+2], si[j*4+3]);
}

// ============ fallback fp32 GEMM (used only if ws too small) ================

__global__ __launch_bounds__(BLK, 1) void angles_gemm(
    const float* __restrict__ x, const float* __restrict__ W,
    const float* __restrict__ b, float* __restrict__ ang,
    int row_base, int pass_rows)
{
    const int t     = threadIdx.x;
    const int lrow0 = blockIdx.x * BLK;
    __shared__ float xs[BLK * LSTRIDE];
    float acc[NA];
#pragma unroll
    for (int a = 0; a < NA; ++a) acc[a] = b[a];
    for (int kc = 0; kc < KDIM; kc += KC) {
        __syncthreads();
#pragma unroll
        for (int it = 0; it < 8; ++it) {
            int f4 = it * BLK + t;
            int r  = f4 >> 3;
            int kq = f4 & 7;
            float4 v = *reinterpret_cast<const float4*>(
                &x[(size_t)(row_base + lrow0 + r) * KDIM + kc + kq * 4]);
            *reinterpret_cast<float4*>(&xs[r * LSTRIDE + kq * 4]) = v;
        }
        __syncthreads();
        float4 xv[KC / 4];
#pragma unroll
        for (int q = 0; q < KC / 4; ++q)
            xv[q] = *reinterpret_cast<const float4*>(&xs[t * LSTRIDE + q * 4]);
#pragma unroll
        for (int a = 0; a < NA; ++a) {
            const float* wa = W + a * KDIM + kc;
            float s = 0.f;
#pragma unroll
            for (int q = 0; q < KC / 4; ++q) {
                s += xv[q].x * wa[q * 4 + 0];
                s += xv[q].y * wa[q * 4 + 1];
                s += xv[q].z * wa[q * 4 + 2];
                s += xv[q].w * wa[q * 4 + 3];
            }
            acc[a] += s;
        }
    }
    const int lrow = lrow0 + t;
#pragma unroll
    for (int a = 0; a < NA; ++a)
        ang[(size_t)a * pass_rows + lrow] = acc[a];
}

// ============================================================================

extern "C" void kernel_launch(void* const* d_in, const int* in_sizes, int n_in,
                              void* d_out, int out_size, void* d_ws, size_t ws_size,
                              hipStream_t stream) {
    const float* x = (const float*)d_in[0];
    const float* W = (const float*)d_in[1];
    const float* b = (const float*)d_in[2];
    float* out = (float*)d_out;
    const int batch = in_sizes[0] / KDIM;          // 65536

    // ws layout: Wh bf16[80*512] | Wl bf16[80*512] | ang f32[80 * batch]
    const size_t wh_bytes  = (size_t)NP * KDIM * 2;
    const size_t need      = 2 * wh_bytes + (size_t)NP * batch * 4;

    if (ws_size >= need && (batch % 128) == 0) {
        unsigned short* Wh = (unsigned short*)d_ws;
        unsigned short* Wl = Wh + (size_t)NP * KDIM;
        float* ang = (float*)((char*)d_ws + 2 * wh_bytes);

        hipLaunchKernelGGL(w_convert, dim3((NP * KDIM + 255) / 256), dim3(256),
                           0, stream, W, Wh, Wl);
        hipLaunchKernelGGL(angles_mfma, dim3(batch / 128), dim3(BLK), 0, stream,
                           x, Wh, Wl, b, ang, batch);
        hipLaunchKernelGGL(circuit_kernel, dim3(batch / BLK), dim3(BLK), 0, stream,
                           ang, out, 0, batch);
        return;
    }

    // fallback: fp32 VALU GEMM, multi-pass through ws
    float* ws = (float*)d_ws;
    size_t max_rows = ws_size / ((size_t)NA * sizeof(float));
    int rows_per_pass = (int)((max_rows / BLK) * BLK);
    if (rows_per_pass > batch) rows_per_pass = batch;
    for (int r0 = 0; r0 < batch; r0 += rows_per_pass) {
        int pr = batch - r0;
        if (pr > rows_per_pass) pr = rows_per_pass;
        hipLaunchKernelGGL(angles_gemm, dim3(pr / BLK), dim3(BLK), 0, stream,
                           x, W, b, ws, r0, pr);
        hipLaunchKernelGGL(circuit_kernel, dim3(pr / BLK), dim3(BLK), 0, stream,
                           ws, out, r0, pr);
    }
}

// Round 4
// 95.183 us; speedup vs baseline: 6.8874x; 1.1706x over previous
//
#include <hip/hip_runtime.h>

#define NA    69      // 3 * (4*6 - 1) angles
#define NP    80      // padded to 5 x 16 MFMA n-tiles
#define KDIM  512
#define BM    128     // gemm rows per block
#define BK    128     // gemm K chunk
#define GT    512     // gemm block threads (8 waves)
#define BLK   256     // circuit block
#define LSTRIDE 33

typedef __attribute__((ext_vector_type(8))) short short8v;   // 8 bf16
typedef __attribute__((ext_vector_type(4))) float f32x4;
typedef __attribute__((ext_vector_type(4))) unsigned short us4;

__device__ __forceinline__ unsigned short bf16_rne(float x) {
    unsigned u = __float_as_uint(x);
    unsigned r = u + 0x7FFF + ((u >> 16) & 1);
    return (unsigned short)(r >> 16);
}

// ==== init: W (69x512 f32) -> bf16 hi/lo in MFMA-fragment order =============
// frag tid = ksg*320 + nt*64 + lane ; lane holds B[n=nt*16+(l&15)][k=ksg*32+(l>>4)*8+j]
__global__ void w_convert(const float* __restrict__ W,
                          unsigned short* __restrict__ Whf,
                          unsigned short* __restrict__ Wlf)
{
    int tid = blockIdx.x * 256 + threadIdx.x;
    if (tid >= 16 * 5 * 64) return;
    int ksg = tid / 320;
    int rem = tid % 320;
    int nt  = rem / 64;
    int l   = rem % 64;
    int n   = nt * 16 + (l & 15);
    int k   = ksg * 32 + (l >> 4) * 8;
#pragma unroll
    for (int j = 0; j < 8; ++j) {
        float w = (n < NA) ? W[(size_t)n * KDIM + k + j] : 0.f;
        unsigned short h = bf16_rne(w);
        float hf = __uint_as_float((unsigned)h << 16);
        Whf[(size_t)tid * 8 + j] = h;
        Wlf[(size_t)tid * 8 + j] = bf16_rne(w - hf);
    }
}

// ==== angles = x @ W^T + b : LDS-staged, swizzled, 3-product bf16 MFMA ======
__global__ __launch_bounds__(GT, 4) void angles_mfma(
    const float* __restrict__ x,
    const unsigned short* __restrict__ Whf, const unsigned short* __restrict__ Wlf,
    const float* __restrict__ b, float* __restrict__ ang, int batch)
{
    __shared__ unsigned short Ah[BM * BK];   // 32 KB, XOR-swizzled 16B blocks
    __shared__ unsigned short Al[BM * BK];   // 32 KB

    const int t    = threadIdx.x;
    const int lane = t & 63;
    const int wave = t >> 6;
    const int mb   = blockIdx.x * BM;

    f32x4 acc[5];
#pragma unroll
    for (int nt = 0; nt < 5; ++nt) acc[nt] = (f32x4){0.f, 0.f, 0.f, 0.f};

#pragma unroll
    for (int c = 0; c < KDIM / BK; ++c) {
        // ---- stage: coalesced global loads (2 rows x 512B per wave),
        //      convert to bf16 hi/lo, swizzled LDS store
#pragma unroll
        for (int q = 0; q < (BM * BK) / (4 * GT); ++q) {   // 8 float4 / thread
            int f    = t + q * GT;
            int row  = f >> 5;          // 32 float4 per 128-col row
            int col4 = f & 31;
            float4 v = *reinterpret_cast<const float4*>(
                &x[(size_t)(mb + row) * KDIM + c * BK + col4 * 4]);
            float vals[4] = {v.x, v.y, v.z, v.w};
            us4 h, lo;
#pragma unroll
            for (int j = 0; j < 4; ++j) {
                unsigned short hh = bf16_rne(vals[j]);
                float hf = __uint_as_float((unsigned)hh << 16);
                h[j]  = hh;
                lo[j] = bf16_rne(vals[j] - hf);
            }
            int sw   = (col4 >> 1) ^ (row & 15);
            int byte = row * (BK * 2) + sw * 16 + (col4 & 1) * 8;
            *reinterpret_cast<us4*>((char*)Ah + byte) = h;
            *reinterpret_cast<us4*>((char*)Al + byte) = lo;
        }
        __syncthreads();

        // ---- compute: 4 MFMA K-steps from LDS A + L2-resident frag-order B
#pragma unroll
        for (int ks = 0; ks < BK / 32; ++ks) {
            int row = wave * 16 + (lane & 15);
            int c8  = ks * 4 + (lane >> 4);
            int sw  = c8 ^ (row & 15);
            int abyte = row * (BK * 2) + sw * 16;
            short8v ah = *reinterpret_cast<const short8v*>((char*)Ah + abyte);
            short8v al = *reinterpret_cast<const short8v*>((char*)Al + abyte);
            int ksg = c * (BK / 32) + ks;
#pragma unroll
            for (int nt = 0; nt < 5; ++nt) {
                size_t boff = ((size_t)(ksg * 5 + nt) * 64 + lane) * 8;
                short8v bh = *reinterpret_cast<const short8v*>(Whf + boff);
                short8v bl = *reinterpret_cast<const short8v*>(Wlf + boff);
                acc[nt] = __builtin_amdgcn_mfma_f32_16x16x32_bf16(ah, bh, acc[nt], 0, 0, 0);
                acc[nt] = __builtin_amdgcn_mfma_f32_16x16x32_bf16(al, bh, acc[nt], 0, 0, 0);
                acc[nt] = __builtin_amdgcn_mfma_f32_16x16x32_bf16(ah, bl, acc[nt], 0, 0, 0);
            }
        }
        __syncthreads();
    }

    // ---- epilogue: C row=(lane>>4)*4+j (m), col=lane&15 (n) -> ang[n][m]
#pragma unroll
    for (int nt = 0; nt < 5; ++nt) {
        int n = nt * 16 + (lane & 15);
        if (n < NA) {
            float bias = b[n];
            int m = mb + wave * 16 + (lane >> 4) * 4;
            f32x4 v = acc[nt];
            float4 o = make_float4(v[0] + bias, v[1] + bias,
                                   v[2] + bias, v[3] + bias);
            *reinterpret_cast<float4*>(&ang[(size_t)n * batch + m]) = o;
        }
    }
}

// ==== circuit: one thread per row, state in registers =======================

template<int W0, int W1>
__device__ __forceinline__ void rxx(float* sr, float* si, float th) {
    float h = 0.5f * th;
    float c, sn;
    __sincosf(h, &sn, &c);
    constexpr int m0 = 1 << (5 - W0);
    constexpr int M  = m0 | (1 << (5 - W1));
#pragma unroll
    for (int j = 0; j < 64; ++j) {
        if (j & m0) continue;
        const int p = j ^ M;
        float ar = sr[j], ai = si[j], br = sr[p], bi = si[p];
        sr[j] = c * ar + sn * bi;
        si[j] = c * ai - sn * br;
        sr[p] = c * br + sn * ai;
        si[p] = c * bi - sn * ar;
    }
}

template<int Wq>
__device__ __forceinline__ void u3(float* sr, float* si,
                                   float th, float ph, float la) {
    float h = 0.5f * th;
    float ct, st, cph, sph, cla, sla;
    __sincosf(h,  &st,  &ct);
    __sincosf(ph, &sph, &cph);
    __sincosf(la, &sla, &cla);
    float cpl = cph * cla - sph * sla;
    float spl = sph * cla + cph * sla;
    float m01r = -cla * st, m01i = -sla * st;
    float m10r =  cph * st, m10i =  sph * st;
    float m11r =  cpl * ct, m11i =  spl * ct;
    constexpr int m = 1 << (5 - Wq);
#pragma unroll
    for (int j = 0; j < 64; ++j) {
        if (j & m) continue;
        const int p = j | m;
        float ar = sr[j], ai = si[j], br = sr[p], bi = si[p];
        sr[j] = ct * ar + m01r * br - m01i * bi;
        si[j] = ct * ai + m01r * bi + m01i * br;
        sr[p] = m10r * ar - m10i * ai + m11r * br - m11i * bi;
        si[p] = m10r * ai + m10i * ar + m11r * bi + m11i * br;
    }
}

__global__ __launch_bounds__(BLK, 2) void circuit_kernel(
    const float* __restrict__ ang, float* __restrict__ out,
    int row_base, int pass_rows)
{
    const int t     = threadIdx.x;
    const int lrow0 = blockIdx.x * BLK;

    __shared__ float as_[NA][BLK];
#pragma unroll 1
    for (int a = 0; a < NA; ++a)
        as_[a][t] = ang[(size_t)a * pass_rows + lrow0 + t];
    __syncthreads();

    float sr[64], si[64];
#pragma unroll
    for (int j = 0; j < 64; ++j) { sr[j] = 0.f; si[j] = 0.f; }
    sr[0] = 1.f;

#define ANG(i) as_[(i)][t]
#pragma unroll 1
    for (int lay = 0; lay < 3; ++lay) {
        const int base = lay * 23;
        rxx<0,1>(sr, si, ANG(base + 0));
        u3<0>(sr, si, ANG(base + 1),  ANG(base + 2),  ANG(base + 3));
        rxx<1,2>(sr, si, ANG(base + 4));
        u3<1>(sr, si, ANG(base + 5),  ANG(base + 6),  ANG(base + 7));
        rxx<2,3>(sr, si, ANG(base + 8));
        u3<2>(sr, si, ANG(base + 9),  ANG(base + 10), ANG(base + 11));
        rxx<3,4>(sr, si, ANG(base + 12));
        u3<3>(sr, si, ANG(base + 13), ANG(base + 14), ANG(base + 15));
        rxx<4,5>(sr, si, ANG(base + 16));
        u3<4>(sr, si, ANG(base + 17), ANG(base + 18), ANG(base + 19));
        u3<5>(sr, si, ANG(base + 20), ANG(base + 21), ANG(base + 22));
    }
#undef ANG

    float* o = out + (size_t)(row_base + lrow0 + t) * 128;
#pragma unroll
    for (int j = 0; j < 16; ++j)
        *reinterpret_cast<float4*>(&o[j * 4]) =
            make_float4(sr[j*4], sr[j*4+1], sr[j*4+2], sr[j*4+3]);
#pragma unroll
    for (int j = 0; j < 16; ++j)
        *reinterpret_cast<float4*>(&o[64 + j * 4]) =
            make_float4(si[j*4], si[j*4+1], si[j*4+2], si[j*4+3]);
}

// ==== fallback fp32 GEMM (only if ws too small) =============================

__global__ __launch_bounds__(BLK, 1) void angles_gemm(
    const float* __restrict__ x, const float* __restrict__ W,
    const float* __restrict__ b, float* __restrict__ ang,
    int row_base, int pass_rows)
{
    const int t     = threadIdx.x;
    const int lrow0 = blockIdx.x * BLK;
    __shared__ float xs[BLK * LSTRIDE];
    float acc[NA];
#pragma unroll
    for (int a = 0; a < NA; ++a) acc[a] = b[a];
    for (int kc = 0; kc < KDIM; kc += 32) {
        __syncthreads();
#pragma unroll
        for (int it = 0; it < 8; ++it) {
            int f4 = it * BLK + t;
            int r  = f4 >> 3;
            int kq = f4 & 7;
            float4 v = *reinterpret_cast<const float4*>(
                &x[(size_t)(row_base + lrow0 + r) * KDIM + kc + kq * 4]);
            *reinterpret_cast<float4*>(&xs[r * LSTRIDE + kq * 4]) = v;
        }
        __syncthreads();
        float4 xv[8];
#pragma unroll
        for (int q = 0; q < 8; ++q)
            xv[q] = *reinterpret_cast<const float4*>(&xs[t * LSTRIDE + q * 4]);
#pragma unroll
        for (int a = 0; a < NA; ++a) {
            const float* wa = W + a * KDIM + kc;
            float s = 0.f;
#pragma unroll
            for (int q = 0; q < 8; ++q) {
                s += xv[q].x * wa[q * 4 + 0];
                s += xv[q].y * wa[q * 4 + 1];
                s += xv[q].z * wa[q * 4 + 2];
                s += xv[q].w * wa[q * 4 + 3];
            }
            acc[a] += s;
        }
    }
    const int lrow = lrow0 + t;
#pragma unroll
    for (int a = 0; a < NA; ++a)
        ang[(size_t)a * pass_rows + lrow] = acc[a];
}

// ============================================================================

extern "C" void kernel_launch(void* const* d_in, const int* in_sizes, int n_in,
                              void* d_out, int out_size, void* d_ws, size_t ws_size,
                              hipStream_t stream) {
    const float* x = (const float*)d_in[0];
    const float* W = (const float*)d_in[1];
    const float* b = (const float*)d_in[2];
    float* out = (float*)d_out;
    const int batch = in_sizes[0] / KDIM;          // 65536

    // ws layout: Whf bf16[16*5*64*8] | Wlf same | ang f32[NP * batch]
    const size_t wf_elems = (size_t)16 * 5 * 64 * 8;   // 40960
    const size_t wf_bytes = wf_elems * 2;
    const size_t need     = 2 * wf_bytes + (size_t)NP * batch * 4;

    if (ws_size >= need && (batch % BM) == 0) {
        unsigned short* Whf = (unsigned short*)d_ws;
        unsigned short* Wlf = Whf + wf_elems;
        float* ang = (float*)((char*)d_ws + 2 * wf_bytes);

        hipLaunchKernelGGL(w_convert, dim3((16 * 5 * 64 + 255) / 256), dim3(256),
                           0, stream, W, Whf, Wlf);
        hipLaunchKernelGGL(angles_mfma, dim3(batch / BM), dim3(GT), 0, stream,
                           x, Whf, Wlf, b, ang, batch);
        hipLaunchKernelGGL(circuit_kernel, dim3(batch / BLK), dim3(BLK), 0, stream,
                           ang, out, 0, batch);
        return;
    }

    // fallback: fp32 VALU GEMM, multi-pass through ws
    float* ws = (float*)d_ws;
    size_t max_rows = ws_size / ((size_t)NA * sizeof(float));
    int rows_per_pass = (int)((max_rows / BLK) * BLK);
    if (rows_per_pass > batch) rows_per_pass = batch;
    for (int r0 = 0; r0 < batch; r0 += rows_per_pass) {
        int pr = batch - r0;
        if (pr > rows_per_pass) pr = rows_per_pass;
        hipLaunchKernelGGL(angles_gemm, dim3(pr / BLK), dim3(BLK), 0, stream,
                           x, W, b, ws, r0, pr);
        hipLaunchKernelGGL(circuit_kernel, dim3(pr / BLK), dim3(BLK), 0, stream,
                           ws, out, r0, pr);
    }
}

// Round 5
// 74.830 us; speedup vs baseline: 8.7608x; 1.2720x over previous
//
#include <hip/hip_runtime.h>

#define NA    69      // 3 * (4*6 - 1) angles
#define NP    80      // padded to 5 x 16 MFMA n-tiles
#define KDIM  512
#define BM    128     // gemm rows per block
#define BK    64      // gemm K chunk
#define GT    512     // gemm block threads (8 waves)
#define CBLK  512     // circuit block threads
#define CROWS 256     // circuit rows per block (2 lanes/row)
#define BLK   256
#define LSTRIDE 33

typedef __attribute__((ext_vector_type(8))) short short8v;   // 8 bf16 = 16B
typedef __attribute__((ext_vector_type(4))) float f32x4;
typedef __attribute__((ext_vector_type(4))) unsigned short us4;

__device__ __forceinline__ unsigned short bf16_rne(float x) {
    unsigned u = __float_as_uint(x);
    unsigned r = u + 0x7FFF + ((u >> 16) & 1);
    return (unsigned short)(r >> 16);
}

// ==== init: W (69x512 f32) -> bf16 hi/lo in MFMA-fragment order =============
// tid = ksg*320 + nt*64 + lane ; holds B[n=nt*16+(l&15)][k=ksg*32+(l>>4)*8+j]
__global__ void w_convert(const float* __restrict__ W,
                          unsigned short* __restrict__ Whf,
                          unsigned short* __restrict__ Wlf)
{
    int tid = blockIdx.x * 256 + threadIdx.x;
    if (tid >= 16 * 5 * 64) return;
    int ksg = tid / 320;
    int rem = tid % 320;
    int nt  = rem / 64;
    int l   = rem % 64;
    int n   = nt * 16 + (l & 15);
    int k   = ksg * 32 + (l >> 4) * 8;
#pragma unroll
    for (int j = 0; j < 8; ++j) {
        float w = (n < NA) ? W[(size_t)n * KDIM + k + j] : 0.f;
        unsigned short h = bf16_rne(w);
        float hf = __uint_as_float((unsigned)h << 16);
        Whf[(size_t)tid * 8 + j] = h;
        Wlf[(size_t)tid * 8 + j] = bf16_rne(w - hf);
    }
}

// ==== angles = x @ W^T + b : A-LDS swizzled + B-LDS shared, bf16 MFMA =======
__global__ __launch_bounds__(GT, 4) void angles_mfma(
    const float* __restrict__ x,
    const unsigned short* __restrict__ Whf, const unsigned short* __restrict__ Wlf,
    const float* __restrict__ b, float* __restrict__ ang, int batch)
{
    __shared__ unsigned short Ah[BM * BK];   // 16 KB, XOR-swizzled 16B blocks
    __shared__ unsigned short Al[BM * BK];   // 16 KB
    __shared__ unsigned short Bh[2 * 5 * 64 * 8];  // 10 KB, frag-linear
    __shared__ unsigned short Bl[2 * 5 * 64 * 8];  // 10 KB

    const int t    = threadIdx.x;
    const int lane = t & 63;
    const int wave = t >> 6;
    const int mb   = blockIdx.x * BM;

    f32x4 acc[5];
#pragma unroll
    for (int nt = 0; nt < 5; ++nt) acc[nt] = (f32x4){0.f, 0.f, 0.f, 0.f};

#pragma unroll 1
    for (int c = 0; c < KDIM / BK; ++c) {
        // ---- stage A: coalesced global, convert to hi/lo, swizzled LDS
#pragma unroll
        for (int q = 0; q < (BM * BK) / (4 * GT); ++q) {   // 4 float4 / thread
            int f    = t + q * GT;
            int row  = f >> 4;          // 16 float4 per 64-col row
            int col4 = f & 15;
            float4 v = *reinterpret_cast<const float4*>(
                &x[(size_t)(mb + row) * KDIM + c * BK + col4 * 4]);
            float vals[4] = {v.x, v.y, v.z, v.w};
            us4 h, lo;
#pragma unroll
            for (int j = 0; j < 4; ++j) {
                unsigned short hh = bf16_rne(vals[j]);
                float hf = __uint_as_float((unsigned)hh << 16);
                h[j]  = hh;
                lo[j] = bf16_rne(vals[j] - hf);
            }
            int sw   = (col4 >> 1) ^ (row & 7);
            int byte = row * (BK * 2) + sw * 16 + (col4 & 1) * 8;
            *reinterpret_cast<us4*>((char*)Ah + byte) = h;
            *reinterpret_cast<us4*>((char*)Al + byte) = lo;
        }
        // ---- stage B: cooperative copy of this chunk's fragments (once/block)
        {
            size_t base = (size_t)c * 5120;      // 2 ksg * 5 nt * 64 * 8
            for (int i = t; i < 640; i += GT) {
                *reinterpret_cast<short8v*>(Bh + i * 8) =
                    *reinterpret_cast<const short8v*>(Whf + base + i * 8);
                *reinterpret_cast<short8v*>(Bl + i * 8) =
                    *reinterpret_cast<const short8v*>(Wlf + base + i * 8);
            }
        }
        __syncthreads();

        // ---- compute: 2 MFMA K-steps from LDS
#pragma unroll
        for (int ks = 0; ks < BK / 32; ++ks) {
            int row = wave * 16 + (lane & 15);
            int c8  = ks * 4 + (lane >> 4);
            int sw  = c8 ^ (row & 7);
            int abyte = row * (BK * 2) + sw * 16;
            short8v ah = *reinterpret_cast<const short8v*>((char*)Ah + abyte);
            short8v al = *reinterpret_cast<const short8v*>((char*)Al + abyte);
#pragma unroll
            for (int nt = 0; nt < 5; ++nt) {
                int boff = ((ks * 5 + nt) * 64 + lane) * 8;
                short8v bh = *reinterpret_cast<const short8v*>(Bh + boff);
                short8v bl = *reinterpret_cast<const short8v*>(Bl + boff);
                acc[nt] = __builtin_amdgcn_mfma_f32_16x16x32_bf16(ah, bh, acc[nt], 0, 0, 0);
                acc[nt] = __builtin_amdgcn_mfma_f32_16x16x32_bf16(al, bh, acc[nt], 0, 0, 0);
                acc[nt] = __builtin_amdgcn_mfma_f32_16x16x32_bf16(ah, bl, acc[nt], 0, 0, 0);
            }
        }
        __syncthreads();
    }

    // ---- epilogue: C row=(lane>>4)*4+j (m), col=lane&15 (n) -> ang[n][m]
#pragma unroll
    for (int nt = 0; nt < 5; ++nt) {
        int n = nt * 16 + (lane & 15);
        if (n < NA) {
            float bias = b[n];
            int m = mb + wave * 16 + (lane >> 4) * 4;
            f32x4 v = acc[nt];
            float4 o = make_float4(v[0] + bias, v[1] + bias,
                                   v[2] + bias, v[3] + bias);
            *reinterpret_cast<float4*>(&ang[(size_t)n * batch + m]) = o;
        }
    }
}

// ==== circuit: 2 lanes per row; lane par=lane>>5 owns qubit-0 bit ===========
// lane holds 32 amps g = par*32 + j (contiguous). Gates on wires 1-5 local;
// RXX(0,1) and U3(0) exchange via __shfl_xor(.,32).

template<int M0, int M1>   // local masks (<=16)
__device__ __forceinline__ void rxx_l(float* sr, float* si, float th) {
    float h = 0.5f * th, c, sn;
    __sincosf(h, &sn, &c);
    constexpr int M = M0 | M1;
#pragma unroll
    for (int j = 0; j < 32; ++j) {
        if (j & M0) continue;
        const int p = j ^ M;
        float ar = sr[j], ai = si[j], br = sr[p], bi = si[p];
        sr[j] = c * ar + sn * bi;
        si[j] = c * ai - sn * br;
        sr[p] = c * br + sn * ai;
        si[p] = c * bi - sn * ar;
    }
}

template<int M>            // local mask (<=16)
__device__ __forceinline__ void u3_l(float* sr, float* si,
                                     float th, float ph, float la) {
    float h = 0.5f * th;
    float ct, st, cph, sph, cla, sla;
    __sincosf(h,  &st,  &ct);
    __sincosf(ph, &sph, &cph);
    __sincosf(la, &sla, &cla);
    float cpl = cph * cla - sph * sla;
    float spl = sph * cla + cph * sla;
    float m01r = -cla * st, m01i = -sla * st;
    float m10r =  cph * st, m10i =  sph * st;
    float m11r =  cpl * ct, m11i =  spl * ct;
#pragma unroll
    for (int j = 0; j < 32; ++j) {
        if (j & M) continue;
        const int p = j | M;
        float ar = sr[j], ai = si[j], br = sr[p], bi = si[p];
        sr[j] = ct * ar + m01r * br - m01i * bi;
        si[j] = ct * ai + m01r * bi + m01i * br;
        sr[p] = m10r * ar - m10i * ai + m11r * br - m11i * bi;
        si[p] = m10r * ai + m10i * ar + m11r * bi + m11i * br;
    }
}

__device__ __forceinline__ void rxx01_x(float* sr, float* si, float th) {
    float h = 0.5f * th, c, sn;
    __sincosf(h, &sn, &c);
#pragma unroll
    for (int j = 0; j < 16; ++j) {
        const int p = j + 16;
        float crj = __shfl_xor(sr[p], 32), cij = __shfl_xor(si[p], 32);
        float crp = __shfl_xor(sr[j], 32), cip = __shfl_xor(si[j], 32);
        float aj = sr[j], bj = si[j], ap = sr[p], bp = si[p];
        sr[j] = c * aj + sn * cij;  si[j] = c * bj - sn * crj;
        sr[p] = c * ap + sn * cip;  si[p] = c * bp - sn * crp;
    }
}

__device__ __forceinline__ void u30_x(float* sr, float* si, int par,
                                      float th, float ph, float la) {
    float h = 0.5f * th;
    float ct, st, cph, sph, cla, sla;
    __sincosf(h,  &st,  &ct);
    __sincosf(ph, &sph, &cph);
    __sincosf(la, &sla, &cla);
    float cpl = cph * cla - sph * sla;
    float spl = sph * cla + cph * sla;
    float m01r = -cla * st, m01i = -sla * st;
    float m10r =  cph * st, m10i =  sph * st;
    float m11r =  cpl * ct, m11i =  spl * ct;
    float Ar = par ? m11r : ct,   Ai = par ? m11i : 0.f;
    float Br = par ? m10r : m01r, Bi = par ? m10i : m01i;
#pragma unroll
    for (int j = 0; j < 32; ++j) {
        float cr = __shfl_xor(sr[j], 32), ci = __shfl_xor(si[j], 32);
        float a = sr[j], bb = si[j];
        sr[j] = Ar * a  - Ai * bb + Br * cr - Bi * ci;
        si[j] = Ar * bb + Ai * a  + Br * ci + Bi * cr;
    }
}

__global__ __launch_bounds__(CBLK, 2) void circuit2(
    const float* __restrict__ ang, float* __restrict__ out,
    int stride, int row_base)
{
    const int t    = threadIdx.x;
    const int lane = t & 63;
    const int wv   = t >> 6;
    const int par  = lane >> 5;
    const int rl   = (lane & 31) + wv * 32;    // local row 0..255
    const int row0 = blockIdx.x * CROWS;

    __shared__ float as_[NA][CROWS];           // 70.6 KB
    for (int i = t; i < NA * CROWS; i += CBLK) {
        int a = i >> 8, r = i & 255;
        as_[a][r] = ang[(size_t)a * stride + row0 + r];
    }
    __syncthreads();

    float sr[32], si[32];
#pragma unroll
    for (int j = 0; j < 32; ++j) { sr[j] = 0.f; si[j] = 0.f; }
    if (par == 0) sr[0] = 1.f;

#define ANG(i) as_[(i)][rl]
#pragma unroll 1
    for (int lay = 0; lay < 3; ++lay) {
        const int base = lay * 23;
        rxx01_x(sr, si, ANG(base + 0));
        u30_x  (sr, si, par, ANG(base + 1), ANG(base + 2), ANG(base + 3));
        rxx_l<16, 8>(sr, si, ANG(base + 4));
        u3_l<16>(sr, si, ANG(base + 5),  ANG(base + 6),  ANG(base + 7));
        rxx_l<8, 4>(sr, si, ANG(base + 8));
        u3_l<8>(sr, si, ANG(base + 9),  ANG(base + 10), ANG(base + 11));
        rxx_l<4, 2>(sr, si, ANG(base + 12));
        u3_l<4>(sr, si, ANG(base + 13), ANG(base + 14), ANG(base + 15));
        rxx_l<2, 1>(sr, si, ANG(base + 16));
        u3_l<2>(sr, si, ANG(base + 17), ANG(base + 18), ANG(base + 19));
        u3_l<1>(sr, si, ANG(base + 20), ANG(base + 21), ANG(base + 22));
    }
#undef ANG

    // out[row][0][g] = real, out[row][1][g] = imag; lane's g-range contiguous
    float* o = out + (size_t)(row_base + row0 + rl) * 128 + par * 32;
#pragma unroll
    for (int q = 0; q < 8; ++q)
        *reinterpret_cast<float4*>(&o[q * 4]) =
            make_float4(sr[q*4], sr[q*4+1], sr[q*4+2], sr[q*4+3]);
#pragma unroll
    for (int q = 0; q < 8; ++q)
        *reinterpret_cast<float4*>(&o[64 + q * 4]) =
            make_float4(si[q*4], si[q*4+1], si[q*4+2], si[q*4+3]);
}

// ==== fallback fp32 GEMM (only if ws too small) =============================

__global__ __launch_bounds__(BLK, 1) void angles_gemm(
    const float* __restrict__ x, const float* __restrict__ W,
    const float* __restrict__ b, float* __restrict__ ang,
    int row_base, int pass_rows)
{
    const int t     = threadIdx.x;
    const int lrow0 = blockIdx.x * BLK;
    __shared__ float xs[BLK * LSTRIDE];
    float acc[NA];
#pragma unroll
    for (int a = 0; a < NA; ++a) acc[a] = b[a];
    for (int kc = 0; kc < KDIM; kc += 32) {
        __syncthreads();
#pragma unroll
        for (int it = 0; it < 8; ++it) {
            int f4 = it * BLK + t;
            int r  = f4 >> 3;
            int kq = f4 & 7;
            float4 v = *reinterpret_cast<const float4*>(
                &x[(size_t)(row_base + lrow0 + r) * KDIM + kc + kq * 4]);
            *reinterpret_cast<float4*>(&xs[r * LSTRIDE + kq * 4]) = v;
        }
        __syncthreads();
        float4 xv[8];
#pragma unroll
        for (int q = 0; q < 8; ++q)
            xv[q] = *reinterpret_cast<const float4*>(&xs[t * LSTRIDE + q * 4]);
#pragma unroll
        for (int a = 0; a < NA; ++a) {
            const float* wa = W + a * KDIM + kc;
            float s = 0.f;
#pragma unroll
            for (int q = 0; q < 8; ++q) {
                s += xv[q].x * wa[q * 4 + 0];
                s += xv[q].y * wa[q * 4 + 1];
                s += xv[q].z * wa[q * 4 + 2];
                s += xv[q].w * wa[q * 4 + 3];
            }
            acc[a] += s;
        }
    }
    const int lrow = lrow0 + t;
#pragma unroll
    for (int a = 0; a < NA; ++a)
        ang[(size_t)a * pass_rows + lrow] = acc[a];
}

// ============================================================================

extern "C" void kernel_launch(void* const* d_in, const int* in_sizes, int n_in,
                              void* d_out, int out_size, void* d_ws, size_t ws_size,
                              hipStream_t stream) {
    const float* x = (const float*)d_in[0];
    const float* W = (const float*)d_in[1];
    const float* b = (const float*)d_in[2];
    float* out = (float*)d_out;
    const int batch = in_sizes[0] / KDIM;          // 65536

    const size_t wf_elems = (size_t)16 * 5 * 64 * 8;   // 40960
    const size_t wf_bytes = wf_elems * 2;
    const size_t need     = 2 * wf_bytes + (size_t)NP * batch * 4;

    if (ws_size >= need && (batch % CROWS) == 0) {
        unsigned short* Whf = (unsigned short*)d_ws;
        unsigned short* Wlf = Whf + wf_elems;
        float* ang = (float*)((char*)d_ws + 2 * wf_bytes);

        hipLaunchKernelGGL(w_convert, dim3((16 * 5 * 64 + 255) / 256), dim3(256),
                           0, stream, W, Whf, Wlf);
        hipLaunchKernelGGL(angles_mfma, dim3(batch / BM), dim3(GT), 0, stream,
                           x, Whf, Wlf, b, ang, batch);
        hipLaunchKernelGGL(circuit2, dim3(batch / CROWS), dim3(CBLK), 0, stream,
                           ang, out, batch, 0);
        return;
    }

    // fallback: fp32 VALU GEMM, multi-pass through ws
    float* ws = (float*)d_ws;
    size_t max_rows = ws_size / ((size_t)NA * sizeof(float));
    int rows_per_pass = (int)((max_rows / CROWS) * CROWS);
    if (rows_per_pass > batch) rows_per_pass = batch;
    for (int r0 = 0; r0 < batch; r0 += rows_per_pass) {
        int pr = batch - r0;
        if (pr > rows_per_pass) pr = rows_per_pass;
        hipLaunchKernelGGL(angles_gemm, dim3(pr / BLK), dim3(BLK), 0, stream,
                           x, W, b, ws, r0, pr);
        hipLaunchKernelGGL(circuit2, dim3(pr / CROWS), dim3(CBLK), 0, stream,
                           ws, out, pr, r0);
    }
}

// Round 6
// 59.735 us; speedup vs baseline: 10.9746x; 1.2527x over previous
//
#include <hip/hip_runtime.h>

#define NA    69      // 3 * (4*6 - 1) angles
#define KDIM  512
#define BM    256     // fused: rows per block
#define BK    64      // gemm K chunk
#define GT    512     // fused block threads (8 waves)
#define CROWS 256
#define BLK   256
#define LSTRIDE 33
#define ASTRIDE 260   // angle LDS row stride (floats): 260%32=4 -> 2-way max

typedef __attribute__((ext_vector_type(8))) short short8v;   // 8 bf16 = 16B
typedef __attribute__((ext_vector_type(4))) float f32x4;
typedef __attribute__((ext_vector_type(4))) unsigned short us4;

__device__ __forceinline__ unsigned short bf16_rne(float x) {
    unsigned u = __float_as_uint(x);
    unsigned r = u + 0x7FFF + ((u >> 16) & 1);
    return (unsigned short)(r >> 16);
}

// ==== init: W (69x512 f32) -> bf16 hi/lo in MFMA-fragment order =============
// tid = ksg*320 + nt*64 + lane ; holds B[n=nt*16+(l&15)][k=ksg*32+(l>>4)*8+j]
__global__ void w_convert(const float* __restrict__ W,
                          unsigned short* __restrict__ Whf,
                          unsigned short* __restrict__ Wlf)
{
    int tid = blockIdx.x * 256 + threadIdx.x;
    if (tid >= 16 * 5 * 64) return;
    int ksg = tid / 320;
    int rem = tid % 320;
    int nt  = rem / 64;
    int l   = rem % 64;
    int n   = nt * 16 + (l & 15);
    int k   = ksg * 32 + (l >> 4) * 8;
#pragma unroll
    for (int j = 0; j < 8; ++j) {
        float w = (n < NA) ? W[(size_t)n * KDIM + k + j] : 0.f;
        unsigned short h = bf16_rne(w);
        float hf = __uint_as_float((unsigned)h << 16);
        Whf[(size_t)tid * 8 + j] = h;
        Wlf[(size_t)tid * 8 + j] = bf16_rne(w - hf);
    }
}

// ==== circuit gate helpers (2 lanes/row; par = lane>>5) =====================

template<int M0, int M1>
__device__ __forceinline__ void rxx_l(float* sr, float* si, float th) {
    float h = 0.5f * th, c, sn;
    __sincosf(h, &sn, &c);
    constexpr int M = M0 | M1;
#pragma unroll
    for (int j = 0; j < 32; ++j) {
        if (j & M0) continue;
        const int p = j ^ M;
        float ar = sr[j], ai = si[j], br = sr[p], bi = si[p];
        sr[j] = c * ar + sn * bi;
        si[j] = c * ai - sn * br;
        sr[p] = c * br + sn * ai;
        si[p] = c * bi - sn * ar;
    }
}

template<int M>
__device__ __forceinline__ void u3_l(float* sr, float* si,
                                     float th, float ph, float la) {
    float h = 0.5f * th;
    float ct, st, cph, sph, cla, sla;
    __sincosf(h,  &st,  &ct);
    __sincosf(ph, &sph, &cph);
    __sincosf(la, &sla, &cla);
    float cpl = cph * cla - sph * sla;
    float spl = sph * cla + cph * sla;
    float m01r = -cla * st, m01i = -sla * st;
    float m10r =  cph * st, m10i =  sph * st;
    float m11r =  cpl * ct, m11i =  spl * ct;
#pragma unroll
    for (int j = 0; j < 32; ++j) {
        if (j & M) continue;
        const int p = j | M;
        float ar = sr[j], ai = si[j], br = sr[p], bi = si[p];
        sr[j] = ct * ar + m01r * br - m01i * bi;
        si[j] = ct * ai + m01r * bi + m01i * br;
        sr[p] = m10r * ar - m10i * ai + m11r * br - m11i * bi;
        si[p] = m10r * ai + m10i * ar + m11r * bi + m11i * br;
    }
}

__device__ __forceinline__ void rxx01_x(float* sr, float* si, float th) {
    float h = 0.5f * th, c, sn;
    __sincosf(h, &sn, &c);
#pragma unroll
    for (int j = 0; j < 16; ++j) {
        const int p = j + 16;
        float crj = __shfl_xor(sr[p], 32), cij = __shfl_xor(si[p], 32);
        float crp = __shfl_xor(sr[j], 32), cip = __shfl_xor(si[j], 32);
        float aj = sr[j], bj = si[j], ap = sr[p], bp = si[p];
        sr[j] = c * aj + sn * cij;  si[j] = c * bj - sn * crj;
        sr[p] = c * ap + sn * cip;  si[p] = c * bp - sn * crp;
    }
}

__device__ __forceinline__ void u30_x(float* sr, float* si, int par,
                                      float th, float ph, float la) {
    float h = 0.5f * th;
    float ct, st, cph, sph, cla, sla;
    __sincosf(h,  &st,  &ct);
    __sincosf(ph, &sph, &cph);
    __sincosf(la, &sla, &cla);
    float cpl = cph * cla - sph * sla;
    float spl = sph * cla + cph * sla;
    float m01r = -cla * st, m01i = -sla * st;
    float m10r =  cph * st, m10i =  sph * st;
    float m11r =  cpl * ct, m11i =  spl * ct;
    float Ar = par ? m11r : ct,   Ai = par ? m11i : 0.f;
    float Br = par ? m10r : m01r, Bi = par ? m10i : m01i;
#pragma unroll
    for (int j = 0; j < 32; ++j) {
        float cr = __shfl_xor(sr[j], 32), ci = __shfl_xor(si[j], 32);
        float a = sr[j], bb = si[j];
        sr[j] = Ar * a  - Ai * bb + Br * cr - Bi * ci;
        si[j] = Ar * bb + Ai * a  + Br * ci + Bi * cr;
    }
}

// ==== fused: GEMM (MFMA, prefetched) -> LDS angles -> circuit ===============

__global__ __launch_bounds__(GT, 2) void qrnn_fused2(
    const float* __restrict__ x,
    const unsigned short* __restrict__ Whf, const unsigned short* __restrict__ Wlf,
    const float* __restrict__ b, float* __restrict__ out)
{
    // union LDS: GEMM phase uses Ah|Al|Bh|Bl (84 KB); circuit phase reuses it
    // as angle store as_[NA][ASTRIDE] (70.1 KB).
    __shared__ __align__(16) char smem[86016];
    unsigned short* Ah = (unsigned short*)smem;              // 32 KB
    unsigned short* Al = (unsigned short*)(smem + 32768);    // 32 KB
    unsigned short* Bh = (unsigned short*)(smem + 65536);    // 10 KB
    unsigned short* Bl = (unsigned short*)(smem + 75776);    // 10 KB
    float* as_ = (float*)smem;

    const int t    = threadIdx.x;
    const int lane = t & 63;
    const int wave = t >> 6;
    const int mb   = blockIdx.x * BM;

    f32x4 acc[2][5];
#pragma unroll
    for (int mt = 0; mt < 2; ++mt)
#pragma unroll
        for (int nt = 0; nt < 5; ++nt) acc[mt][nt] = (f32x4){0.f, 0.f, 0.f, 0.f};

    float4 vA[8];
    short8v vBh0, vBl0, vBh1, vBl1;

    // prefetch chunk 0
#pragma unroll
    for (int q = 0; q < 8; ++q) {
        int f = t + q * GT, row = f >> 4, col4 = f & 15;
        vA[q] = *reinterpret_cast<const float4*>(
            &x[(size_t)(mb + row) * KDIM + col4 * 4]);
    }
    vBh0 = *reinterpret_cast<const short8v*>(Whf + t * 8);
    vBl0 = *reinterpret_cast<const short8v*>(Wlf + t * 8);
    if (t < 128) {
        vBh1 = *reinterpret_cast<const short8v*>(Whf + (t + 512) * 8);
        vBl1 = *reinterpret_cast<const short8v*>(Wlf + (t + 512) * 8);
    }

#pragma unroll
    for (int c = 0; c < KDIM / BK; ++c) {
        // ---- write staged chunk c to LDS (convert A to bf16 hi/lo)
#pragma unroll
        for (int q = 0; q < 8; ++q) {
            int f = t + q * GT, row = f >> 4, col4 = f & 15;
            float vals[4] = {vA[q].x, vA[q].y, vA[q].z, vA[q].w};
            us4 h, lo;
#pragma unroll
            for (int j = 0; j < 4; ++j) {
                unsigned short hh = bf16_rne(vals[j]);
                float hf = __uint_as_float((unsigned)hh << 16);
                h[j]  = hh;
                lo[j] = bf16_rne(vals[j] - hf);
            }
            int sw   = (col4 >> 1) ^ (row & 7);
            int byte = row * (BK * 2) + sw * 16 + (col4 & 1) * 8;
            *reinterpret_cast<us4*>((char*)Ah + byte) = h;
            *reinterpret_cast<us4*>((char*)Al + byte) = lo;
        }
        *reinterpret_cast<short8v*>(Bh + t * 8) = vBh0;
        *reinterpret_cast<short8v*>(Bl + t * 8) = vBl0;
        if (t < 128) {
            *reinterpret_cast<short8v*>(Bh + (t + 512) * 8) = vBh1;
            *reinterpret_cast<short8v*>(Bl + (t + 512) * 8) = vBl1;
        }
        // ---- issue chunk c+1 loads (in flight across the compute phase)
        if (c + 1 < KDIM / BK) {
#pragma unroll
            for (int q = 0; q < 8; ++q) {
                int f = t + q * GT, row = f >> 4, col4 = f & 15;
                vA[q] = *reinterpret_cast<const float4*>(
                    &x[(size_t)(mb + row) * KDIM + (c + 1) * BK + col4 * 4]);
            }
            size_t base = (size_t)(c + 1) * 5120;
            vBh0 = *reinterpret_cast<const short8v*>(Whf + base + t * 8);
            vBl0 = *reinterpret_cast<const short8v*>(Wlf + base + t * 8);
            if (t < 128) {
                vBh1 = *reinterpret_cast<const short8v*>(Whf + base + (t + 512) * 8);
                vBl1 = *reinterpret_cast<const short8v*>(Wlf + base + (t + 512) * 8);
            }
        }
        __syncthreads();

        // ---- compute chunk c: 2 K-steps x 2 m-tiles x 5 n-tiles x 3 products
#pragma unroll
        for (int ks = 0; ks < BK / 32; ++ks) {
            short8v ah[2], al[2];
#pragma unroll
            for (int mt = 0; mt < 2; ++mt) {
                int row = wave * 32 + mt * 16 + (lane & 15);
                int c8  = ks * 4 + (lane >> 4);
                int sw  = c8 ^ (row & 7);
                int abyte = row * (BK * 2) + sw * 16;
                ah[mt] = *reinterpret_cast<const short8v*>((char*)Ah + abyte);
                al[mt] = *reinterpret_cast<const short8v*>((char*)Al + abyte);
            }
#pragma unroll
            for (int nt = 0; nt < 5; ++nt) {
                int boff = ((ks * 5 + nt) * 64 + lane) * 8;
                short8v bh = *reinterpret_cast<const short8v*>(Bh + boff);
                short8v bl = *reinterpret_cast<const short8v*>(Bl + boff);
#pragma unroll
                for (int mt = 0; mt < 2; ++mt) {
                    acc[mt][nt] = __builtin_amdgcn_mfma_f32_16x16x32_bf16(ah[mt], bh, acc[mt][nt], 0, 0, 0);
                    acc[mt][nt] = __builtin_amdgcn_mfma_f32_16x16x32_bf16(al[mt], bh, acc[mt][nt], 0, 0, 0);
                    acc[mt][nt] = __builtin_amdgcn_mfma_f32_16x16x32_bf16(ah[mt], bl, acc[mt][nt], 0, 0, 0);
                }
            }
        }
        __syncthreads();
    }

    // ---- epilogue: angles into LDS (A/B buffers dead after last barrier)
#pragma unroll
    for (int mt = 0; mt < 2; ++mt)
#pragma unroll
        for (int nt = 0; nt < 5; ++nt) {
            int n = nt * 16 + (lane & 15);
            if (n < NA) {
                float bias = b[n];
                int m = wave * 32 + mt * 16 + (lane >> 4) * 4;
                f32x4 v = acc[mt][nt];
#pragma unroll
                for (int j = 0; j < 4; ++j)
                    as_[n * ASTRIDE + m + j] = v[j] + bias;
            }
        }
    __syncthreads();

    // ---- circuit phase: 2 lanes/row (proven R5 structure), angles from LDS
    const int par = lane >> 5;
    const int rl  = (lane & 31) + wave * 32;    // local row 0..255

    float sr[32], si[32];
#pragma unroll
    for (int j = 0; j < 32; ++j) { sr[j] = 0.f; si[j] = 0.f; }
    if (par == 0) sr[0] = 1.f;

#define ANG(i) as_[(i) * ASTRIDE + rl]
#pragma unroll 1
    for (int lay = 0; lay < 3; ++lay) {
        const int base = lay * 23;
        rxx01_x(sr, si, ANG(base + 0));
        u30_x  (sr, si, par, ANG(base + 1), ANG(base + 2), ANG(base + 3));
        rxx_l<16, 8>(sr, si, ANG(base + 4));
        u3_l<16>(sr, si, ANG(base + 5),  ANG(base + 6),  ANG(base + 7));
        rxx_l<8, 4>(sr, si, ANG(base + 8));
        u3_l<8>(sr, si, ANG(base + 9),  ANG(base + 10), ANG(base + 11));
        rxx_l<4, 2>(sr, si, ANG(base + 12));
        u3_l<4>(sr, si, ANG(base + 13), ANG(base + 14), ANG(base + 15));
        rxx_l<2, 1>(sr, si, ANG(base + 16));
        u3_l<2>(sr, si, ANG(base + 17), ANG(base + 18), ANG(base + 19));
        u3_l<1>(sr, si, ANG(base + 20), ANG(base + 21), ANG(base + 22));
    }
#undef ANG

    float* o = out + (size_t)(mb + rl) * 128 + par * 32;
#pragma unroll
    for (int q = 0; q < 8; ++q)
        *reinterpret_cast<float4*>(&o[q * 4]) =
            make_float4(sr[q*4], sr[q*4+1], sr[q*4+2], sr[q*4+3]);
#pragma unroll
    for (int q = 0; q < 8; ++q)
        *reinterpret_cast<float4*>(&o[64 + q * 4]) =
            make_float4(si[q*4], si[q*4+1], si[q*4+2], si[q*4+3]);
}

// ==== fallback (ws too small): fp32 VALU GEMM + global-ang circuit ==========

__global__ __launch_bounds__(BLK, 1) void angles_gemm(
    const float* __restrict__ x, const float* __restrict__ W,
    const float* __restrict__ b, float* __restrict__ ang,
    int row_base, int pass_rows)
{
    const int t     = threadIdx.x;
    const int lrow0 = blockIdx.x * BLK;
    __shared__ float xs[BLK * LSTRIDE];
    float acc[NA];
#pragma unroll
    for (int a = 0; a < NA; ++a) acc[a] = b[a];
    for (int kc = 0; kc < KDIM; kc += 32) {
        __syncthreads();
#pragma unroll
        for (int it = 0; it < 8; ++it) {
            int f4 = it * BLK + t;
            int r  = f4 >> 3;
            int kq = f4 & 7;
            float4 v = *reinterpret_cast<const float4*>(
                &x[(size_t)(row_base + lrow0 + r) * KDIM + kc + kq * 4]);
            *reinterpret_cast<float4*>(&xs[r * LSTRIDE + kq * 4]) = v;
        }
        __syncthreads();
        float4 xv[8];
#pragma unroll
        for (int q = 0; q < 8; ++q)
            xv[q] = *reinterpret_cast<const float4*>(&xs[t * LSTRIDE + q * 4]);
#pragma unroll
        for (int a = 0; a < NA; ++a) {
            const float* wa = W + a * KDIM + kc;
            float s = 0.f;
#pragma unroll
            for (int q = 0; q < 8; ++q) {
                s += xv[q].x * wa[q * 4 + 0];
                s += xv[q].y * wa[q * 4 + 1];
                s += xv[q].z * wa[q * 4 + 2];
                s += xv[q].w * wa[q * 4 + 3];
            }
            acc[a] += s;
        }
    }
    const int lrow = lrow0 + t;
#pragma unroll
    for (int a = 0; a < NA; ++a)
        ang[(size_t)a * pass_rows + lrow] = acc[a];
}

__global__ __launch_bounds__(GT, 2) void circuit2g(
    const float* __restrict__ ang, float* __restrict__ out,
    int stride, int row_base)
{
    const int t    = threadIdx.x;
    const int lane = t & 63;
    const int wv   = t >> 6;
    const int par  = lane >> 5;
    const int rl   = (lane & 31) + wv * 32;
    const int row0 = blockIdx.x * CROWS;

    __shared__ float as_[NA][CROWS];
    for (int i = t; i < NA * CROWS; i += GT) {
        int a = i >> 8, r = i & 255;
        as_[a][r] = ang[(size_t)a * stride + row0 + r];
    }
    __syncthreads();

    float sr[32], si[32];
#pragma unroll
    for (int j = 0; j < 32; ++j) { sr[j] = 0.f; si[j] = 0.f; }
    if (par == 0) sr[0] = 1.f;

#define ANG(i) as_[(i)][rl]
#pragma unroll 1
    for (int lay = 0; lay < 3; ++lay) {
        const int base = lay * 23;
        rxx01_x(sr, si, ANG(base + 0));
        u30_x  (sr, si, par, ANG(base + 1), ANG(base + 2), ANG(base + 3));
        rxx_l<16, 8>(sr, si, ANG(base + 4));
        u3_l<16>(sr, si, ANG(base + 5),  ANG(base + 6),  ANG(base + 7));
        rxx_l<8, 4>(sr, si, ANG(base + 8));
        u3_l<8>(sr, si, ANG(base + 9),  ANG(base + 10), ANG(base + 11));
        rxx_l<4, 2>(sr, si, ANG(base + 12));
        u3_l<4>(sr, si, ANG(base + 13), ANG(base + 14), ANG(base + 15));
        rxx_l<2, 1>(sr, si, ANG(base + 16));
        u3_l<2>(sr, si, ANG(base + 17), ANG(base + 18), ANG(base + 19));
        u3_l<1>(sr, si, ANG(base + 20), ANG(base + 21), ANG(base + 22));
    }
#undef ANG

    float* o = out + (size_t)(row_base + row0 + rl) * 128 + par * 32;
#pragma unroll
    for (int q = 0; q < 8; ++q)
        *reinterpret_cast<float4*>(&o[q * 4]) =
            make_float4(sr[q*4], sr[q*4+1], sr[q*4+2], sr[q*4+3]);
#pragma unroll
    for (int q = 0; q < 8; ++q)
        *reinterpret_cast<float4*>(&o[64 + q * 4]) =
            make_float4(si[q*4], si[q*4+1], si[q*4+2], si[q*4+3]);
}

// ============================================================================

extern "C" void kernel_launch(void* const* d_in, const int* in_sizes, int n_in,
                              void* d_out, int out_size, void* d_ws, size_t ws_size,
                              hipStream_t stream) {
    const float* x = (const float*)d_in[0];
    const float* W = (const float*)d_in[1];
    const float* b = (const float*)d_in[2];
    float* out = (float*)d_out;
    const int batch = in_sizes[0] / KDIM;          // 65536

    const size_t wf_elems = (size_t)16 * 5 * 64 * 8;   // 40960 per buffer
    const size_t need     = 2 * wf_elems * 2;          // 160 KB

    if (ws_size >= need && (batch % BM) == 0) {
        unsigned short* Whf = (unsigned short*)d_ws;
        unsigned short* Wlf = Whf + wf_elems;
        hipLaunchKernelGGL(w_convert, dim3((16 * 5 * 64 + 255) / 256), dim3(256),
                           0, stream, W, Whf, Wlf);
        hipLaunchKernelGGL(qrnn_fused2, dim3(batch / BM), dim3(GT), 0, stream,
                           x, Whf, Wlf, b, out);
        return;
    }

    // fallback: fp32 VALU GEMM + circuit via global angles, multi-pass
    float* ws = (float*)d_ws;
    size_t max_rows = ws_size / ((size_t)NA * sizeof(float));
    int rows_per_pass = (int)((max_rows / CROWS) * CROWS);
    if (rows_per_pass > batch) rows_per_pass = batch;
    if (rows_per_pass < CROWS) return;   // cannot run
    for (int r0 = 0; r0 < batch; r0 += rows_per_pass) {
        int pr = batch - r0;
        if (pr > rows_per_pass) pr = rows_per_pass;
        hipLaunchKernelGGL(angles_gemm, dim3(pr / BLK), dim3(BLK), 0, stream,
                           x, W, b, ws, r0, pr);
        hipLaunchKernelGGL(circuit2g, dim3(pr / CROWS), dim3(GT), 0, stream,
                           ws, out, pr, r0);
    }
}